// Round 8
// baseline (212.986 us; speedup 1.0000x reference)
//
#include <hip/hip_runtime.h>
#include <hip/hip_bf16.h>
#include <stdint.h>

typedef unsigned short u16;
typedef __attribute__((ext_vector_type(8))) short bf16x8;
typedef __attribute__((ext_vector_type(4))) float f32x4;

typedef const __attribute__((address_space(1))) unsigned int* gu32p;
typedef __attribute__((address_space(3))) unsigned int* lu32p;

__device__ __forceinline__ void gl_lds16(const u16* g, u16* l) {
  // async global->LDS DMA, 16B/lane, LDS dest = wave-uniform base + lane*16
  __builtin_amdgcn_global_load_lds((gu32p)(const void*)g, (lu32p)(void*)l, 16, 0, 0);
}

__device__ __forceinline__ u16 f2bf(float f) {
  union { float f; unsigned u; } v; v.f = f;
  unsigned r = v.u + 0x7fffu + ((v.u >> 16) & 1u);
  return (u16)(r >> 16);
}
// packed f32x2 -> bf16x2 (one v_cvt_pk), scattered to two u16 slots
__device__ __forceinline__ void st2bf(u16* p0, u16* p1, float a, float b) {
  union { __hip_bfloat162 h; u16 u[2]; } cv;
  cv.h = __float22bfloat162_rn(make_float2(a, b));
  *p0 = cv.u[0]; *p1 = cv.u[1];
}

// ---------------- fp32 -> bf16 convert (x + 4 weights) and RoPE cos/sin table
__global__ void convert_kernel(const float4* __restrict__ x, const float4* __restrict__ wq,
                               const float4* __restrict__ wk, const float4* __restrict__ wv,
                               const float4* __restrict__ wp,
                               u16* __restrict__ xb, u16* __restrict__ wqb, u16* __restrict__ wkb,
                               u16* __restrict__ wvb, u16* __restrict__ wpb,
                               float2* __restrict__ tab) {
  int i = blockIdx.x * 256 + threadIdx.x;
  const int NX = 1048576, NW = 262144, NCONV = NX + 4 * NW;
  if (i >= NCONV) {
    int j = i - NCONV;              // 0..65535 : t*32 + d
    int d = j & 31, t = j >> 5;
    float ang = (float)t * expf(-0.28782313662425572f * (float)d);  // ln(10000)/32
    tab[j] = make_float2(cosf(ang), sinf(ang));
    return;
  }
  const float4* src; u16* dst; int off;
  if (i < NX)            { src = x;  dst = xb;  off = i; }
  else if (i < NX + NW)  { src = wq; dst = wqb; off = i - NX; }
  else if (i < NX + 2*NW){ src = wk; dst = wkb; off = i - NX - NW; }
  else if (i < NX + 3*NW){ src = wv; dst = wvb; off = i - NX - 2*NW; }
  else                   { src = wp; dst = wpb; off = i - NX - 3*NW; }
  float4 v = src[off];
  ushort4 ov = make_ushort4(f2bf(v.x), f2bf(v.y), f2bf(v.z), f2bf(v.w));
  *(ushort4*)&dst[off * 4] = ov;
}

// ---------------- NT GEMM: C[M,N] = A[M,K] * B[N,K]^T + bias, K=N=1024, M=4096
// Double-buffered single-barrier K-loop: DMA of tile k+1 overlaps compute of
// tile k within the block. FUSE_ROPE: rotary in epilogue for z<2. TRANS_V:
// z==2 stores output transposed as Vt[(b*1024 + c)*2048 + t].
template<int FUSE_ROPE, int OUT_BF16, int TRANS_V>
__global__ __launch_bounds__(256) void gemm_bt_kernel(
    const u16* __restrict__ A,
    const u16* __restrict__ B0, const u16* __restrict__ B1, const u16* __restrict__ B2,
    const float* __restrict__ bias0, const float* __restrict__ bias1, const float* __restrict__ bias2,
    void* out0, void* out1, void* out2, const float2* __restrict__ tab)
{
  __shared__ __align__(16) u16 As[2][4096];   // 128 x 32 per buf (64B rows)
  __shared__ __align__(16) u16 Bs[2][4096];
  const int z = blockIdx.z;
  const u16* Bw = (z == 0) ? B0 : (z == 1) ? B1 : B2;
  const float* bias = (z == 0) ? bias0 : (z == 1) ? bias1 : bias2;
  void* outv = (z == 0) ? out0 : (z == 1) ? out1 : out2;
  const int tid = threadIdx.x, lane = tid & 63, w = tid >> 6;
  const int wr = w >> 1, wc = w & 1;
  const int quad = lane >> 4, l15 = lane & 15;
  const int m0 = blockIdx.y * 128, n0 = blockIdx.x * 128;
  const int sr = lane >> 2, sc = (lane & 3) * 8;

  auto stg = [&](int kt, int bf) {
    const int k0 = kt * 32;
    #pragma unroll
    for (int p = 0; p < 2; p++) {
      gl_lds16(A  + (m0 + p*64 + w*16 + sr) * 1024 + k0 + sc, &As[bf][p*2048 + w*512]);
      gl_lds16(Bw + (n0 + p*64 + w*16 + sr) * 1024 + k0 + sc, &Bs[bf][p*2048 + w*512]);
    }
  };

  f32x4 acc[4][4] = {};
  stg(0, 0);
  for (int kt = 0; kt < 32; kt++) {
    __syncthreads();                 // tile kt landed; other buf free
    if (kt < 31) stg(kt + 1, (kt + 1) & 1);
    const int bf = kt & 1;
    bf16x8 af[4], bfr[4];
    #pragma unroll
    for (int mt = 0; mt < 4; mt++)
      af[mt] = *(const bf16x8*)&As[bf][(wr*64 + mt*16 + l15) * 32 + quad*8];
    #pragma unroll
    for (int nt = 0; nt < 4; nt++)
      bfr[nt] = *(const bf16x8*)&Bs[bf][(wc*64 + nt*16 + l15) * 32 + quad*8];
    #pragma unroll
    for (int mt = 0; mt < 4; mt++)
      #pragma unroll
      for (int nt = 0; nt < 4; nt++)
        acc[mt][nt] = __builtin_amdgcn_mfma_f32_16x16x32_bf16(af[mt], bfr[nt], acc[mt][nt], 0, 0, 0);
  }

  if (TRANS_V && z == 2) {
    // direct transposed store: lane holds 4 consecutive t (quad*4+r) for col c
    const int bb = m0 >> 11, tg0 = (m0 & 2047) + wr*64 + quad*4;
    #pragma unroll
    for (int nt = 0; nt < 4; nt++) {
      const int c = n0 + wc*64 + nt*16 + l15;
      const float bv = bias[c];
      u16* vrow = (u16*)outv + (size_t)(bb*1024 + c) * 2048 + tg0;
      #pragma unroll
      for (int mt = 0; mt < 4; mt++) {
        ushort4 pk;
        pk.x = f2bf(acc[mt][nt][0] + bv); pk.y = f2bf(acc[mt][nt][1] + bv);
        pk.z = f2bf(acc[mt][nt][2] + bv); pk.w = f2bf(acc[mt][nt][3] + bv);
        *(ushort4*)&vrow[mt*16] = pk;
      }
    }
    return;
  }

  #pragma unroll
  for (int mt = 0; mt < 4; mt++) {
    #pragma unroll
    for (int r = 0; r < 4; r++) {
      const int row = m0 + wr*64 + mt*16 + quad*4 + r;
      float v[4];
      #pragma unroll
      for (int nt = 0; nt < 4; nt++)
        v[nt] = acc[mt][nt][r] + bias[n0 + wc*64 + nt*16 + l15];
      if (FUSE_ROPE && z < 2) {
        const int t = row & 2047;
        #pragma unroll
        for (int nt = 0; nt < 2; nt++) {
          const int d = nt*16 + l15;
          float2 cs = tab[t*32 + d];
          float x0 = v[nt], x1 = v[nt+2];
          v[nt]   = x0 * cs.x - x1 * cs.y;
          v[nt+2] = x1 * cs.x + x0 * cs.y;
        }
      }
      #pragma unroll
      for (int nt = 0; nt < 4; nt++) {
        const int col = n0 + wc*64 + nt*16 + l15;
        if (OUT_BF16) ((u16*)outv)[row * 1024 + col] = f2bf(v[nt]);
        else          ((float*)outv)[row * 1024 + col] = v[nt];
      }
    }
  }
}

// ---------------- causal flash attention, UNIFORM-WAVE PAIRED 128-row q-tiles.
// Block x handles tiles A (qt=x) and B (qt=15-x); ALL 8 waves own a 16-row
// slice of BOTH tiles. Per stripe j: compute tile B always, tile A while
// j<=qtA (block-uniform branch, no divergence, no idle waves in the tail).
// Shared K/V staging (all 8 waves DMA), double-buffered, XOR swizzled.
// K-frags/V-frags read from LDS once per stripe, reused for both tiles.
// No online softmax (bounded scores); row-sum via MFMA with all-ones B-frag.
__global__ __launch_bounds__(512) void attn_kernel(
    const u16* __restrict__ qg, const u16* __restrict__ kg,
    const u16* __restrict__ vtg, u16* __restrict__ yg)
{
  __shared__ __align__(16) u16 K_lds[2][128 * 64];     // [s][d], swizzle g^(s&7)
  __shared__ __align__(16) u16 V_lds[2][64 * 128];     // [d][s], swizzle g^(d&15)
  __shared__ __align__(16) u16 P_lds[8][2][16 * 128];  // [wave][tile], swizzle g^(row&7)
  const int x = blockIdx.x;                // 0..7
  const int hh = blockIdx.y, b = blockIdx.z;
  const int tid = threadIdx.x, lane = tid & 63, w = tid >> 6;   // w: 0..7
  const int quad = lane >> 4, l15 = lane & 15;
  const int bh = b * (2048 * 1024) + hh * 64;
  const int vtb = (b * 16 + hh) * 131072;  // Vt: [b,h][64 d][2048 t]

  const int qtA = x, qtB = 15 - x;
  const int wrow = w*16;                   // wave's 16-row slice within a tile

  bf16x8 qfA[2], qfB[2];
  {
    const int rA = qtA*128 + wrow + l15;
    const int rB = qtB*128 + wrow + l15;
    qfA[0] = *(const bf16x8*)&qg[bh + rA*1024 + quad*8];
    qfA[1] = *(const bf16x8*)&qg[bh + rA*1024 + 32 + quad*8];
    qfB[0] = *(const bf16x8*)&qg[bh + rB*1024 + quad*8];
    qfB[1] = *(const bf16x8*)&qg[bh + rB*1024 + 32 + quad*8];
  }
  f32x4 oA[4] = {}, oB[4] = {};            // un-normalized output per tile
  f32x4 l5A = {}, l5B = {};                // row-sums (replicated across cols)

  bf16x8 ones;
  #pragma unroll
  for (int i2 = 0; i2 < 8; i2++) ones[i2] = (short)0x3F80;  // bf16 1.0

  const float c = 0.18033688011112042f;    // (1/sqrt(64)) * log2(e)

  auto do_stage = [&](int j, int bf) {
    #pragma unroll
    for (int p = 0; p < 2; p++) {          // K: 16 segs of 1024B
      const int seg = w*2 + p;             // 0..15
      const int r = seg*8 + (lane >> 3);   // row 0..127
      const int g = (lane & 7) ^ (r & 7);
      gl_lds16(kg + bh + (j*128 + r) * 1024 + g*8, &K_lds[bf][seg*512]);
    }
    #pragma unroll
    for (int p = 0; p < 2; p++) {          // Vt: 16 segs of 4 rows x 128
      const int seg = w*2 + p;
      const int r = seg*4 + (lane >> 4);   // row 0..63
      const int g = (lane & 15) ^ (r & 15);
      gl_lds16(vtg + vtb + r * 2048 + j*128 + g*8, &V_lds[bf][seg*512]);
    }
  };

  do_stage(0, 0);
  for (int j = 0; j <= qtB; j++) {
    __syncthreads();                       // stripe j landed; other buf free
    if (j < qtB) do_stage(j + 1, (j + 1) & 1);
    const int bf = j & 1;
    const bool doA = (j <= qtA);           // block-uniform

    // ---- S = Q K^T : K-frags read once, shared by both tiles
    f32x4 sA[8], sB[8];
    #pragma unroll
    for (int nt = 0; nt < 8; nt++) {
      const int krow = (nt*16 + l15) * 64;
      const int g0 = ((quad)     ^ (l15 & 7)) * 8;
      const int g1 = ((4 + quad) ^ (l15 & 7)) * 8;
      bf16x8 kf0 = *(const bf16x8*)&K_lds[bf][krow + g0];
      bf16x8 kf1 = *(const bf16x8*)&K_lds[bf][krow + g1];
      f32x4 z = {};
      z = __builtin_amdgcn_mfma_f32_16x16x32_bf16(qfB[0], kf0, z, 0, 0, 0);
      z = __builtin_amdgcn_mfma_f32_16x16x32_bf16(qfB[1], kf1, z, 0, 0, 0);
      sB[nt] = z;
      if (doA) {
        f32x4 za = {};
        za = __builtin_amdgcn_mfma_f32_16x16x32_bf16(qfA[0], kf0, za, 0, 0, 0);
        za = __builtin_amdgcn_mfma_f32_16x16x32_bf16(qfA[1], kf1, za, 0, 0, 0);
        sA[nt] = za;
      }
    }
    const int trow = wrow + quad*4;
    if (j == qtB) {                        // diagonal mask for tile B
      #pragma unroll
      for (int nt = 0; nt < 8; nt++)
        #pragma unroll
        for (int r = 0; r < 4; r++)
          if (nt*16 + l15 > trow + r) sB[nt][r] = -1e30f;
    }
    if (doA && j == qtA) {                 // diagonal mask for tile A
      #pragma unroll
      for (int nt = 0; nt < 8; nt++)
        #pragma unroll
        for (int r = 0; r < 4; r++)
          if (nt*16 + l15 > trow + r) sA[nt][r] = -1e30f;
    }
    // ---- p = exp2(s*c), write P slots (swizzled)
    #pragma unroll
    for (int r = 0; r < 4; r++) {
      const int R = quad*4 + r;
      u16* ppB = &P_lds[w][1][R*128 + (l15 & 7)];
      #pragma unroll
      for (int nt = 0; nt < 8; nt += 2) {
        float p0 = exp2f(sB[nt][r] * c);
        float p1 = exp2f(sB[nt+1][r] * c);
        const int g0 = ((nt*2     + (l15 >> 3)) ^ (R & 7)) * 8;
        const int g1 = (((nt+1)*2 + (l15 >> 3)) ^ (R & 7)) * 8;
        st2bf(ppB + g0, ppB + g1, p0, p1);
      }
    }
    if (doA) {
      #pragma unroll
      for (int r = 0; r < 4; r++) {
        const int R = quad*4 + r;
        u16* ppA = &P_lds[w][0][R*128 + (l15 & 7)];
        #pragma unroll
        for (int nt = 0; nt < 8; nt += 2) {
          float p0 = exp2f(sA[nt][r] * c);
          float p1 = exp2f(sA[nt+1][r] * c);
          const int g0 = ((nt*2     + (l15 >> 3)) ^ (R & 7)) * 8;
          const int g1 = (((nt+1)*2 + (l15 >> 3)) ^ (R & 7)) * 8;
          st2bf(ppA + g0, ppA + g1, p0, p1);
        }
      }
    }
    // ---- O += P V ; l += P 1 : V-frags read once, shared by both tiles
    #pragma unroll
    for (int ss = 0; ss < 4; ss++) {
      const int pg = ((ss*4 + quad) ^ (l15 & 7)) * 8;
      bf16x8 pfB = *(const bf16x8*)&P_lds[w][1][l15*128 + pg];
      l5B = __builtin_amdgcn_mfma_f32_16x16x32_bf16(pfB, ones, l5B, 0, 0, 0);
      bf16x8 pfA = {};
      if (doA) {
        pfA = *(const bf16x8*)&P_lds[w][0][l15*128 + pg];
        l5A = __builtin_amdgcn_mfma_f32_16x16x32_bf16(pfA, ones, l5A, 0, 0, 0);
      }
      #pragma unroll
      for (int dt = 0; dt < 4; dt++) {
        const int vg = ((ss*4 + quad) ^ l15) * 8;
        bf16x8 vf = *(const bf16x8*)&V_lds[bf][(dt*16 + l15)*128 + vg];
        oB[dt] = __builtin_amdgcn_mfma_f32_16x16x32_bf16(pfB, vf, oB[dt], 0, 0, 0);
        if (doA) oA[dt] = __builtin_amdgcn_mfma_f32_16x16x32_bf16(pfA, vf, oA[dt], 0, 0, 0);
      }
    }
  }

  #pragma unroll
  for (int r = 0; r < 4; r++) {
    float ia = 1.0f / l5A[r], ib = 1.0f / l5B[r];
    u16* yA = &yg[bh + (qtA*128 + wrow + quad*4 + r) * 1024 + l15];
    u16* yB = &yg[bh + (qtB*128 + wrow + quad*4 + r) * 1024 + l15];
    st2bf(yA,      yA + 16, oA[0][r] * ia, oA[1][r] * ia);
    st2bf(yA + 32, yA + 48, oA[2][r] * ia, oA[3][r] * ia);
    st2bf(yB,      yB + 16, oB[0][r] * ib, oB[1][r] * ib);
    st2bf(yB + 32, yB + 48, oB[2][r] * ib, oB[3][r] * ib);
  }
}

extern "C" void kernel_launch(void* const* d_in, const int* in_sizes, int n_in,
                              void* d_out, int out_size, void* d_ws, size_t ws_size,
                              hipStream_t stream) {
  const float* x  = (const float*)d_in[0];
  const float* Wq = (const float*)d_in[1];
  const float* bq = (const float*)d_in[2];
  const float* Wk = (const float*)d_in[3];
  const float* bk = (const float*)d_in[4];
  const float* Wv = (const float*)d_in[5];
  const float* bv = (const float*)d_in[6];
  const float* Wp = (const float*)d_in[7];
  const float* bp = (const float*)d_in[8];

  char* ws = (char*)d_ws;
  u16* xb  = (u16*)(ws);                   // 8 MB, reused as attention output y
  u16* wqb = (u16*)(ws + (8u  << 20));
  u16* wkb = (u16*)(ws + (10u << 20));
  u16* wvb = (u16*)(ws + (12u << 20));
  u16* wpb = (u16*)(ws + (14u << 20));
  u16* qb  = (u16*)(ws + (16u << 20));
  u16* kb  = (u16*)(ws + (24u << 20));
  u16* vtb = (u16*)(ws + (32u << 20));     // V transposed: [b,h,d][t], 8 MB
  float2* tab = (float2*)(ws + (40u << 20));
  u16* yb = xb;

  convert_kernel<<<8448, 256, 0, stream>>>((const float4*)x, (const float4*)Wq, (const float4*)Wk,
                                           (const float4*)Wv, (const float4*)Wp,
                                           xb, wqb, wkb, wvb, wpb, tab);
  gemm_bt_kernel<1, 1, 1><<<dim3(8, 32, 3), 256, 0, stream>>>(xb, wqb, wkb, wvb, bq, bk, bv,
                                                              (void*)qb, (void*)kb, (void*)vtb, tab);
  attn_kernel<<<dim3(8, 16, 2), 512, 0, stream>>>(qb, kb, vtb, yb);
  gemm_bt_kernel<0, 0, 0><<<dim3(8, 32, 1), 256, 0, stream>>>(yb, wpb, wpb, wpb, bp, bp, bp,
                                                              (void*)d_out, (void*)d_out, (void*)d_out, tab);
}